// Round 5
// baseline (1082.967 us; speedup 1.0000x reference)
//
#include <hip/hip_runtime.h>
#include <stdint.h>

#define DIM 128

static inline int cdiv(long a, long b) { return (int)((a + b - 1) / b); }

// clang ext-vector types: __builtin_nontemporal_* requires real vector types.
typedef float f32x4 __attribute__((ext_vector_type(4)));
typedef unsigned u32x2 __attribute__((ext_vector_type(2)));

// ---- bf16 pack/unpack (RNE) ----
__device__ __forceinline__ unsigned pk_bf16(float a, float b) {
  unsigned ua = __float_as_uint(a), ub = __float_as_uint(b);
  ua = (ua + 0x7FFFu + ((ua >> 16) & 1u)) >> 16;
  ub = (ub + 0x7FFFu + ((ub >> 16) & 1u)) >> 16;
  return ua | (ub << 16);
}
__device__ __forceinline__ float bf_lo(unsigned u) { return __uint_as_float(u << 16); }
__device__ __forceinline__ float bf_hi(unsigned u) { return __uint_as_float(u & 0xFFFF0000u); }

// ---- index conversion: handles both int32 and int64 edge_index layouts ----
__global__ __launch_bounds__(256) void convert_idx_kernel(
    const int* __restrict__ raw, int* __restrict__ out, long n_total) {
  bool is64;
  {
    int l = threadIdx.x & 63;
    int v = raw[2 * l + 1];               // high words if int64 (values < 2^31)
    unsigned long long m = __ballot(v == 0);
    is64 = (m == ~0ull);
  }
  long i = blockIdx.x * 256L + threadIdx.x;
  if (i < n_total) out[i] = is64 ? raw[2 * i] : raw[i];
}

// cnt[0..E) = hyperedge sizes, cnt[E..E+N) = node degrees
__global__ __launch_bounds__(256) void count_kernel(
    const int* __restrict__ src, const int* __restrict__ edg,
    int* __restrict__ cnt, int E, int nnz) {
  int g = blockIdx.x * 256 + threadIdx.x;
  if (g < nnz) {
    atomicAdd(&cnt[edg[g]], 1);
    atomicAdd(&cnt[E + src[g]], 1);
  }
}

// ---- 3-kernel exclusive scan of cnt[0..M) into P[0..M], P[M]=total ----
__global__ __launch_bounds__(256) void scanA_kernel(
    const int* __restrict__ cnt, int* __restrict__ P, int* __restrict__ BS, int M) {
  __shared__ int lds[256];
  int t = threadIdx.x;
  long base = blockIdx.x * 1024L;
  int v[4], ts = 0;
#pragma unroll
  for (int j = 0; j < 4; ++j) {
    long i = base + t * 4 + j;
    v[j] = (i < M) ? cnt[i] : 0;
    ts += v[j];
  }
  lds[t] = ts;
  __syncthreads();
  for (int off = 1; off < 256; off <<= 1) {
    int x = (t >= off) ? lds[t - off] : 0;
    __syncthreads();
    lds[t] += x;
    __syncthreads();
  }
  int run = lds[t] - ts;  // exclusive base for this thread
#pragma unroll
  for (int j = 0; j < 4; ++j) {
    long i = base + t * 4 + j;
    if (i < M) P[i] = run;
    run += v[j];
  }
  if (t == 255) BS[blockIdx.x] = lds[255];
}

__global__ void scanB_kernel(int* __restrict__ BS, int* __restrict__ P,
                             int nblocks, int M) {
  if (threadIdx.x == 0) {
    int run = 0;
    for (int i = 0; i < nblocks; ++i) { int x = BS[i]; BS[i] = run; run += x; }
    P[M] = run;
  }
}

__global__ __launch_bounds__(256) void scanC_kernel(
    int* __restrict__ P, const int* __restrict__ BS, int M) {
  long i = blockIdx.x * 256L + threadIdx.x;
  if (i < M) P[i] += BS[i >> 10];
}

// adj_e[P[e]..] = member nodes of edge e ; adj_n[P[E+i]-nnz..] = edges of node i
__global__ __launch_bounds__(256) void fill_adj_kernel(
    const int* __restrict__ src, const int* __restrict__ edg,
    const int* __restrict__ P, int* __restrict__ cnt,
    int* __restrict__ adj_e, int* __restrict__ adj_n, int E, int nnz) {
  int g = blockIdx.x * 256 + threadIdx.x;
  if (g < nnz) {
    int e = edg[g], s = src[g];
    int pe = P[e] + atomicAdd(&cnt[e], 1);
    adj_e[pe] = s;
    int pn = P[E + s] - nnz + atomicAdd(&cnt[E + s], 1);
    adj_n[pn] = e;
  }
}

// Wp = diag(a) @ W ; rvec = d @ W   (folds previous layer's BN affine into GEMM)
__global__ void prep_w_kernel(const float* __restrict__ W,
                              const float* __restrict__ aff_a,
                              const float* __restrict__ aff_d,
                              float* __restrict__ Wp, float* __restrict__ rvec,
                              int has_aff) {
  int j = threadIdx.x;  // 0..127
  float racc = 0.0f;
  for (int c = 0; c < DIM; ++c) {
    float w = W[c * DIM + j];
    float a = has_aff ? aff_a[c] : 1.0f;
    float d = has_aff ? aff_d[c] : 0.0f;
    Wp[c * DIM + j] = a * w;
    racc = fmaf(d, w, racc);
  }
  rvec[j] = racc;
}

// Split bf16 node-feature tables: xlo holds ch 0..63, xhi ch 64..127,
// each row 64 ch = 16 uint2 = 128 B (fits 2 cache lines).
// Normal stores: the next gather wants these in L3.
__global__ __launch_bounds__(256) void cast_x_kernel(
    const float* __restrict__ X, uint2* __restrict__ xlo,
    uint2* __restrict__ xhi, long total2) {
  long i = blockIdx.x * 256L + threadIdx.x;
  if (i >= total2) return;
  long row = i >> 5;
  int c = (int)(i & 31);
  float4 v = ((const float4*)X)[i];
  uint2 o;
  o.x = pk_bf16(v.x, v.y);
  o.y = pk_bf16(v.z, v.w);
  if (c < 16) xlo[row * 16 + c] = o;
  else        xhi[row * 16 + c - 16] = o;
}

// ag[e][c] = Binv_e * sum_{i in e} x[i][c]. Reads split bf16 tables.
// 16 lanes/edge, 16 slots/block. Uniform clamped-4 loop (sentinel row SENT=N
// is all zeros): 8 independent loads in flight per thread, no serial tail.
__global__ __launch_bounds__(256) void edge_gather_kernel(
    const uint2* __restrict__ xlo, const uint2* __restrict__ xhi,
    const int* __restrict__ P, const int* __restrict__ adj_e,
    float* __restrict__ ag, int E, int SENT) {
  int slot = threadIdx.x >> 4;
  int l = threadIdx.x & 15;
  int e = blockIdx.x * 16 + slot;
  if (e >= E) return;
  int p0 = P[e], p1 = P[e + 1];
  float4 aL = {0.f, 0.f, 0.f, 0.f}, aH = {0.f, 0.f, 0.f, 0.f};
  int kl = p1 - 1;
  for (int k = p0; k < p1; k += 4) {
    int n0 = adj_e[min(k, kl)];
    int n1 = (k + 1 <= kl) ? adj_e[k + 1] : SENT;
    int n2 = (k + 2 <= kl) ? adj_e[k + 2] : SENT;
    int n3 = (k + 3 <= kl) ? adj_e[k + 3] : SENT;
    uint2 a0 = xlo[(size_t)n0 * 16 + l];
    uint2 b0 = xhi[(size_t)n0 * 16 + l];
    uint2 a1 = xlo[(size_t)n1 * 16 + l];
    uint2 b1 = xhi[(size_t)n1 * 16 + l];
    uint2 a2 = xlo[(size_t)n2 * 16 + l];
    uint2 b2 = xhi[(size_t)n2 * 16 + l];
    uint2 a3 = xlo[(size_t)n3 * 16 + l];
    uint2 b3 = xhi[(size_t)n3 * 16 + l];
    aL.x += (bf_lo(a0.x) + bf_lo(a1.x)) + (bf_lo(a2.x) + bf_lo(a3.x));
    aL.y += (bf_hi(a0.x) + bf_hi(a1.x)) + (bf_hi(a2.x) + bf_hi(a3.x));
    aL.z += (bf_lo(a0.y) + bf_lo(a1.y)) + (bf_lo(a2.y) + bf_lo(a3.y));
    aL.w += (bf_hi(a0.y) + bf_hi(a1.y)) + (bf_hi(a2.y) + bf_hi(a3.y));
    aH.x += (bf_lo(b0.x) + bf_lo(b1.x)) + (bf_lo(b2.x) + bf_lo(b3.x));
    aH.y += (bf_hi(b0.x) + bf_hi(b1.x)) + (bf_hi(b2.x) + bf_hi(b3.x));
    aH.z += (bf_lo(b0.y) + bf_lo(b1.y)) + (bf_lo(b2.y) + bf_lo(b3.y));
    aH.w += (bf_hi(b0.y) + bf_hi(b1.y)) + (bf_hi(b2.y) + bf_hi(b3.y));
  }
  float binv = (p1 > p0) ? 1.0f / (float)(p1 - p0) : 0.0f;
  f32x4 oL, oH;
  oL.x = aL.x * binv; oL.y = aL.y * binv; oL.z = aL.z * binv; oL.w = aL.w * binv;
  oH.x = aH.x * binv; oH.y = aH.y * binv; oH.z = aH.z * binv; oH.w = aH.w * binv;
  __builtin_nontemporal_store(oL, &((f32x4*)ag)[(size_t)e * 32 + l]);
  __builtin_nontemporal_store(oH, &((f32x4*)ag)[(size_t)e * 32 + 16 + l]);
}

// ef split tables = (ag @ Wp + rvec) bf16, zeroed for empty edges (deg==0).
// fp32 accumulate; store goes to Ylo (ch<64) or Yhi (ch>=64), row = 32 uints.
__global__ __launch_bounds__(256) void gemm128_kernel(
    const float* __restrict__ X, const float* __restrict__ Wp,
    const float* __restrict__ rvec, const int* __restrict__ Pdeg,
    unsigned* __restrict__ Ylo, unsigned* __restrict__ Yhi, int nrows) {
  __shared__ float sW[32 * DIM];   // sW[kk*128 + j]
  __shared__ float sX[DIM * 36];   // sX[rr*36 + kk], 36 keeps 16B align + pad
  const int t = threadIdx.x;
  const int row0 = blockIdx.x * DIM;
  const int tx = t & 15, ty = t >> 4;
  const int col0 = tx * 8, lr0 = ty * 8;
  float acc[8][8];
#pragma unroll
  for (int i = 0; i < 8; ++i)
#pragma unroll
    for (int j = 0; j < 8; ++j) acc[i][j] = 0.0f;

  for (int kc = 0; kc < 4; ++kc) {
    __syncthreads();
    {
      const float4* W4 = (const float4*)(Wp + kc * 32 * DIM);
      float4* sW4 = (float4*)sW;
#pragma unroll
      for (int i = 0; i < 4; ++i) sW4[t + i * 256] = W4[t + i * 256];
    }
#pragma unroll
    for (int i = 0; i < 4; ++i) {
      int q = t + i * 256;            // 0..1023 float4 slots
      int rr = q >> 3, kq = q & 7;
      int gr = row0 + rr; if (gr >= nrows) gr = nrows - 1;  // stores are guarded
      float4 v = *(const float4*)&X[(size_t)gr * DIM + kc * 32 + kq * 4];
      *(float4*)&sX[rr * 36 + kq * 4] = v;
    }
    __syncthreads();
    for (int kk = 0; kk < 32; ++kk) {
      float4 w0 = *(const float4*)&sW[kk * DIM + col0];
      float4 w1 = *(const float4*)&sW[kk * DIM + col0 + 4];
      float wv[8] = {w0.x, w0.y, w0.z, w0.w, w1.x, w1.y, w1.z, w1.w};
      float xv[8];
#pragma unroll
      for (int i = 0; i < 8; ++i) xv[i] = sX[(lr0 + i) * 36 + kk];
#pragma unroll
      for (int i = 0; i < 8; ++i)
#pragma unroll
        for (int j = 0; j < 8; ++j) acc[i][j] = fmaf(xv[i], wv[j], acc[i][j]);
    }
  }
  float4 r0 = *(const float4*)&rvec[col0];
  float4 r1 = *(const float4*)&rvec[col0 + 4];
  unsigned* tab = (col0 < 64) ? Ylo : Yhi;
  const int cb = (col0 & 63) >> 1;  // uint offset within 32-uint row
#pragma unroll
  for (int i = 0; i < 8; ++i) {
    int gr = row0 + lr0 + i;
    if (gr < nrows) {
      // empty segment must produce 0 (reference: Binv=0 ⇒ e_feat=0),
      // not rvec — guard with the degree.
      float nz = (Pdeg[gr + 1] > Pdeg[gr]) ? 1.0f : 0.0f;
      float o0x = (acc[i][0] + r0.x) * nz, o0y = (acc[i][1] + r0.y) * nz;
      float o0z = (acc[i][2] + r0.z) * nz, o0w = (acc[i][3] + r0.w) * nz;
      float o1x = (acc[i][4] + r1.x) * nz, o1y = (acc[i][5] + r1.y) * nz;
      float o1z = (acc[i][6] + r1.z) * nz, o1w = (acc[i][7] + r1.w) * nz;
      uint4 st;
      st.x = pk_bf16(o0x, o0y);
      st.y = pk_bf16(o0z, o0w);
      st.z = pk_bf16(o1x, o1y);
      st.w = pk_bf16(o1z, o1w);
      *(uint4*)&tab[(size_t)gr * 32 + cb] = st;
    }
  }
}

// One 64-channel pass: z[i][coff..coff+63] = bf16(relu(Dinv*sum ef + b)),
// fused BN stats into sum[coff..]. ef table = 2.56 MB -> per-XCD L2 resident,
// so steady-state gathers are L2 hits (~250cy) instead of L3/HBM.
// 16 lanes/node, 16 slots/block; uniform clamped-8 loop via sentinel row
// SENT=E (all zeros): 8 independent loads in flight, no serial tail.
__global__ __launch_bounds__(256) void node_gather_kernel(
    const uint2* __restrict__ ef, const int* __restrict__ P,
    const int* __restrict__ adj_n, const float* __restrict__ b, int coff,
    uint2* __restrict__ ztab, float* __restrict__ sum,
    float* __restrict__ sumsq, int E, int N, int nnz, int SENT) {
  __shared__ float lsum[64], lsumsq[64];
  int t = threadIdx.x;
  if (t < 64) { lsum[t] = 0.f; lsumsq[t] = 0.f; }
  __syncthreads();
  int slot = t >> 4;
  int l = t & 15;
  float4 bc = ((const float4*)(b + coff))[l];
  float4 s1 = {0.f, 0.f, 0.f, 0.f}, s2 = {0.f, 0.f, 0.f, 0.f};
  for (int i = blockIdx.x * 16 + slot; i < N; i += gridDim.x * 16) {
    int p0 = P[E + i] - nnz, p1 = P[E + i + 1] - nnz;
    float4 a = {0.f, 0.f, 0.f, 0.f};
    int kl = p1 - 1;
    for (int k = p0; k < p1; k += 8) {
      int e0 = adj_n[min(k, kl)];
      int e1 = (k + 1 <= kl) ? adj_n[k + 1] : SENT;
      int e2 = (k + 2 <= kl) ? adj_n[k + 2] : SENT;
      int e3 = (k + 3 <= kl) ? adj_n[k + 3] : SENT;
      int e4 = (k + 4 <= kl) ? adj_n[k + 4] : SENT;
      int e5 = (k + 5 <= kl) ? adj_n[k + 5] : SENT;
      int e6 = (k + 6 <= kl) ? adj_n[k + 6] : SENT;
      int e7 = (k + 7 <= kl) ? adj_n[k + 7] : SENT;
      uint2 q0 = ef[(size_t)e0 * 16 + l];
      uint2 q1 = ef[(size_t)e1 * 16 + l];
      uint2 q2 = ef[(size_t)e2 * 16 + l];
      uint2 q3 = ef[(size_t)e3 * 16 + l];
      uint2 q4 = ef[(size_t)e4 * 16 + l];
      uint2 q5 = ef[(size_t)e5 * 16 + l];
      uint2 q6 = ef[(size_t)e6 * 16 + l];
      uint2 q7 = ef[(size_t)e7 * 16 + l];
      a.x += ((bf_lo(q0.x) + bf_lo(q1.x)) + (bf_lo(q2.x) + bf_lo(q3.x))) +
             ((bf_lo(q4.x) + bf_lo(q5.x)) + (bf_lo(q6.x) + bf_lo(q7.x)));
      a.y += ((bf_hi(q0.x) + bf_hi(q1.x)) + (bf_hi(q2.x) + bf_hi(q3.x))) +
             ((bf_hi(q4.x) + bf_hi(q5.x)) + (bf_hi(q6.x) + bf_hi(q7.x)));
      a.z += ((bf_lo(q0.y) + bf_lo(q1.y)) + (bf_lo(q2.y) + bf_lo(q3.y))) +
             ((bf_lo(q4.y) + bf_lo(q5.y)) + (bf_lo(q6.y) + bf_lo(q7.y)));
      a.w += ((bf_hi(q0.y) + bf_hi(q1.y)) + (bf_hi(q2.y) + bf_hi(q3.y))) +
             ((bf_hi(q4.y) + bf_hi(q5.y)) + (bf_hi(q6.y) + bf_hi(q7.y)));
    }
    float dinv = (p1 > p0) ? 1.0f / (float)(p1 - p0) : 0.0f;
    float4 v;
    v.x = fmaxf(fmaf(dinv, a.x, bc.x), 0.f);
    v.y = fmaxf(fmaf(dinv, a.y, bc.y), 0.f);
    v.z = fmaxf(fmaf(dinv, a.z, bc.z), 0.f);
    v.w = fmaxf(fmaf(dinv, a.w, bc.w), 0.f);
    uint2 o;
    o.x = pk_bf16(v.x, v.y);
    o.y = pk_bf16(v.z, v.w);
    ztab[(size_t)i * 16 + l] = o;   // normal store: next gather reads via L3
    s1.x += v.x; s1.y += v.y; s1.z += v.z; s1.w += v.w;
    s2.x = fmaf(v.x, v.x, s2.x); s2.y = fmaf(v.y, v.y, s2.y);
    s2.z = fmaf(v.z, v.z, s2.z); s2.w = fmaf(v.w, v.w, s2.w);
  }
  int c0 = l * 4;
  atomicAdd(&lsum[c0 + 0], s1.x); atomicAdd(&lsum[c0 + 1], s1.y);
  atomicAdd(&lsum[c0 + 2], s1.z); atomicAdd(&lsum[c0 + 3], s1.w);
  atomicAdd(&lsumsq[c0 + 0], s2.x); atomicAdd(&lsumsq[c0 + 1], s2.y);
  atomicAdd(&lsumsq[c0 + 2], s2.z); atomicAdd(&lsumsq[c0 + 3], s2.w);
  __syncthreads();
  if (t < 64) {
    atomicAdd(&sum[coff + t], lsum[t]);
    atomicAdd(&sumsq[coff + t], lsumsq[t]);
  }
}

// aff_a = g*rsqrt(var+eps); aff_d = beta - mu*aff_a
__global__ void finalize_bn_kernel(const float* __restrict__ sum,
                                   const float* __restrict__ sumsq,
                                   const float* __restrict__ g,
                                   const float* __restrict__ beta,
                                   float* __restrict__ aff_a, float* __restrict__ aff_d,
                                   int n) {
  int c = threadIdx.x;
  float inv_n = 1.0f / (float)n;
  float mu = sum[c] * inv_n;
  float var = fmaf(sumsq[c], inv_n, -mu * mu);
  float a = g[c] * rsqrtf(var + 1e-5f);
  aff_a[c] = a;
  aff_d[c] = fmaf(-mu, a, beta[c]);
}

// out = aff_a*z + aff_d (split bf16 z -> fp32 out, nt store: final output)
__global__ __launch_bounds__(256) void apply_affine_kernel(
    const uint2* __restrict__ zlo, const uint2* __restrict__ zhi,
    const float* __restrict__ aff_a, const float* __restrict__ aff_d,
    float* __restrict__ out, long total2) {
  long i = blockIdx.x * 256L + threadIdx.x;
  if (i >= total2) return;
  long row = i >> 5;
  int c = (int)(i & 31);
  uint2 q = (c < 16) ? zlo[row * 16 + c] : zhi[row * 16 + c - 16];
  float4 a = ((const float4*)aff_a)[c];
  float4 d = ((const float4*)aff_d)[c];
  f32x4 o;
  o.x = fmaf(a.x, bf_lo(q.x), d.x);
  o.y = fmaf(a.y, bf_hi(q.x), d.y);
  o.z = fmaf(a.z, bf_lo(q.y), d.z);
  o.w = fmaf(a.w, bf_hi(q.y), d.w);
  __builtin_nontemporal_store(o, &((f32x4*)out)[i]);
}

extern "C" void kernel_launch(void* const* d_in, const int* in_sizes, int n_in,
                              void* d_out, int out_size, void* d_ws, size_t ws_size,
                              hipStream_t stream) {
  const int NNZv = in_sizes[0] / 2;
  const int Nv   = in_sizes[1] / DIM;
  const int Ev   = in_sizes[2] / DIM;
  const int* eidx_raw = (const int*)d_in[0];
  const float* node_attr = (const float*)d_in[1];

  // ---- workspace layout (~47 MB total) ----
  float* bufE  = (float*)d_ws;                 // E*128 f32 (ag)
  float* Wp    = bufE + (size_t)Ev * DIM;      // 128*128
  float* rvec  = Wp + DIM * DIM;               // 128
  float* sums  = rvec + 128;                   // 128
  float* sumsq = sums + 128;                   // 128
  float* aff_a = sumsq + 128;                  // 128
  float* aff_d = aff_a + 128;                  // 128
  // src/edg/cnt dead after fill_adj -> reused as the split ef tables,
  // each (E+1) rows x 32 uints (row E = zero sentinel). 2*(E+1)*32 uints
  // = 5.12 MB <= src+edg+cnt region (5.28 MB).
  int* src   = (int*)(aff_d + 128);            // NNZ
  int* edg   = src + NNZv;                     // NNZ
  int* cnt   = edg + NNZv;                     // E+N (padded to x4)
  int* P     = cnt + (((size_t)Ev + Nv + 3) & ~(size_t)3);  // E+N+1 (padded)
  int* BS    = P + (((size_t)Ev + Nv + 1 + 3) & ~(size_t)3); // <=256 block sums
  int* adj_e = BS + 256;                       // NNZ
  int* adj_n = adj_e + NNZv;                   // NNZ
  unsigned* ef_lo = (unsigned*)src;            // (E+1)*32 uints
  unsigned* ef_hi = ef_lo + (size_t)(Ev + 1) * 32;
  // split bf16 node-feature tables, each (N+1) rows x 16 uint2 (row N = zero)
  uint2* xh_lo = (uint2*)(adj_n + NNZv);
  uint2* xh_hi = xh_lo + (size_t)(Nv + 1) * 16;

  const int M = Ev + Nv;
  const int nbA = cdiv(M, 1024);

  convert_idx_kernel<<<cdiv(2L * NNZv, 256), 256, 0, stream>>>(eidx_raw, src, 2L * NNZv);
  hipMemsetAsync(cnt, 0, (size_t)M * 4, stream);
  count_kernel<<<cdiv(NNZv, 256), 256, 0, stream>>>(src, edg, cnt, Ev, NNZv);
  scanA_kernel<<<nbA, 256, 0, stream>>>(cnt, P, BS, M);
  scanB_kernel<<<1, 64, 0, stream>>>(BS, P, nbA, M);
  scanC_kernel<<<cdiv(M, 256), 256, 0, stream>>>(P, BS, M);
  hipMemsetAsync(cnt, 0, (size_t)M * 4, stream);
  fill_adj_kernel<<<cdiv(NNZv, 256), 256, 0, stream>>>(src, edg, P, cnt, adj_e, adj_n, Ev, NNZv);
  cast_x_kernel<<<cdiv((long)Nv * 32, 256), 256, 0, stream>>>(
      node_attr, xh_lo, xh_hi, (long)Nv * 32);
  // zero sentinel rows (edge row E, node row N) used by the clamped gathers
  hipMemsetAsync(ef_lo + (size_t)Ev * 32, 0, 128, stream);
  hipMemsetAsync(ef_hi + (size_t)Ev * 32, 0, 128, stream);
  hipMemsetAsync(xh_lo + (size_t)Nv * 16, 0, 128, stream);
  hipMemsetAsync(xh_hi + (size_t)Nv * 16, 0, 128, stream);

  for (int l = 0; l < 3; ++l) {
    const float* W    = (const float*)d_in[3 + l * 4];
    const float* b    = (const float*)d_in[4 + l * 4];
    const float* g    = (const float*)d_in[5 + l * 4];
    const float* beta = (const float*)d_in[6 + l * 4];

    prep_w_kernel<<<1, 128, 0, stream>>>(W, aff_a, aff_d, Wp, rvec, l > 0 ? 1 : 0);
    edge_gather_kernel<<<cdiv(Ev, 16), 256, 0, stream>>>(
        xh_lo, xh_hi, P, adj_e, bufE, Ev, Nv);
    gemm128_kernel<<<cdiv(Ev, DIM), 256, 0, stream>>>(bufE, Wp, rvec, P, ef_lo, ef_hi, Ev);
    hipMemsetAsync(sums, 0, 256 * 4, stream);
    node_gather_kernel<<<2048, 256, 0, stream>>>(
        (const uint2*)ef_lo, P, adj_n, b, 0,  xh_lo, sums, sumsq, Ev, Nv, NNZv, Ev);
    node_gather_kernel<<<2048, 256, 0, stream>>>(
        (const uint2*)ef_hi, P, adj_n, b, 64, xh_hi, sums, sumsq, Ev, Nv, NNZv, Ev);
    finalize_bn_kernel<<<1, 128, 0, stream>>>(sums, sumsq, g, beta, aff_a, aff_d, Nv);
  }
  apply_affine_kernel<<<cdiv((long)Nv * 32, 256), 256, 0, stream>>>(
      xh_lo, xh_hi, aff_a, aff_d, (float*)d_out, (long)Nv * 32);
}

// Round 6
// 827.714 us; speedup vs baseline: 1.3084x; 1.3084x over previous
//
#include <hip/hip_runtime.h>
#include <stdint.h>

#define DIM 128

static inline int cdiv(long a, long b) { return (int)((a + b - 1) / b); }

// clang ext-vector types: __builtin_nontemporal_* requires real vector types.
typedef float f32x4 __attribute__((ext_vector_type(4)));

// ---- bf16 pack/unpack (RNE) ----
__device__ __forceinline__ unsigned pk_bf16(float a, float b) {
  unsigned ua = __float_as_uint(a), ub = __float_as_uint(b);
  ua = (ua + 0x7FFFu + ((ua >> 16) & 1u)) >> 16;
  ub = (ub + 0x7FFFu + ((ub >> 16) & 1u)) >> 16;
  return ua | (ub << 16);
}
__device__ __forceinline__ float bf_lo(unsigned u) { return __uint_as_float(u << 16); }
__device__ __forceinline__ float bf_hi(unsigned u) { return __uint_as_float(u & 0xFFFF0000u); }

// ---- index conversion: handles both int32 and int64 edge_index layouts ----
__global__ __launch_bounds__(256) void convert_idx_kernel(
    const int* __restrict__ raw, int* __restrict__ out, long n_total) {
  bool is64;
  {
    int l = threadIdx.x & 63;
    int v = raw[2 * l + 1];               // high words if int64 (values < 2^31)
    unsigned long long m = __ballot(v == 0);
    is64 = (m == ~0ull);
  }
  long i = blockIdx.x * 256L + threadIdx.x;
  if (i < n_total) out[i] = is64 ? raw[2 * i] : raw[i];
}

// cnt[0..E) = hyperedge sizes, cnt[E..E+N) = node degrees
__global__ __launch_bounds__(256) void count_kernel(
    const int* __restrict__ src, const int* __restrict__ edg,
    int* __restrict__ cnt, int E, int nnz) {
  int g = blockIdx.x * 256 + threadIdx.x;
  if (g < nnz) {
    atomicAdd(&cnt[edg[g]], 1);
    atomicAdd(&cnt[E + src[g]], 1);
  }
}

// ---- 3-kernel exclusive scan of cnt[0..M) into P[0..M], P[M]=total ----
__global__ __launch_bounds__(256) void scanA_kernel(
    const int* __restrict__ cnt, int* __restrict__ P, int* __restrict__ BS, int M) {
  __shared__ int lds[256];
  int t = threadIdx.x;
  long base = blockIdx.x * 1024L;
  int v[4], ts = 0;
#pragma unroll
  for (int j = 0; j < 4; ++j) {
    long i = base + t * 4 + j;
    v[j] = (i < M) ? cnt[i] : 0;
    ts += v[j];
  }
  lds[t] = ts;
  __syncthreads();
  for (int off = 1; off < 256; off <<= 1) {
    int x = (t >= off) ? lds[t - off] : 0;
    __syncthreads();
    lds[t] += x;
    __syncthreads();
  }
  int run = lds[t] - ts;  // exclusive base for this thread
#pragma unroll
  for (int j = 0; j < 4; ++j) {
    long i = base + t * 4 + j;
    if (i < M) P[i] = run;
    run += v[j];
  }
  if (t == 255) BS[blockIdx.x] = lds[255];
}

__global__ void scanB_kernel(int* __restrict__ BS, int* __restrict__ P,
                             int nblocks, int M) {
  if (threadIdx.x == 0) {
    int run = 0;
    for (int i = 0; i < nblocks; ++i) { int x = BS[i]; BS[i] = run; run += x; }
    P[M] = run;
  }
}

__global__ __launch_bounds__(256) void scanC_kernel(
    int* __restrict__ P, const int* __restrict__ BS, int M) {
  long i = blockIdx.x * 256L + threadIdx.x;
  if (i < M) P[i] += BS[i >> 10];
}

// adj_e[P[e]..] = member nodes of edge e ; adj_n[P[E+i]-nnz..] = edges of node i
__global__ __launch_bounds__(256) void fill_adj_kernel(
    const int* __restrict__ src, const int* __restrict__ edg,
    const int* __restrict__ P, int* __restrict__ cnt,
    int* __restrict__ adj_e, int* __restrict__ adj_n, int E, int nnz) {
  int g = blockIdx.x * 256 + threadIdx.x;
  if (g < nnz) {
    int e = edg[g], s = src[g];
    int pe = P[e] + atomicAdd(&cnt[e], 1);
    adj_e[pe] = s;
    int pn = P[E + s] - nnz + atomicAdd(&cnt[E + s], 1);
    adj_n[pn] = e;
  }
}

// Wp = diag(a) @ W ; rvec = d @ W   (folds previous layer's BN affine into GEMM)
__global__ void prep_w_kernel(const float* __restrict__ W,
                              const float* __restrict__ aff_a,
                              const float* __restrict__ aff_d,
                              float* __restrict__ Wp, float* __restrict__ rvec,
                              int has_aff) {
  int j = threadIdx.x;  // 0..127
  float racc = 0.0f;
  for (int c = 0; c < DIM; ++c) {
    float w = W[c * DIM + j];
    float a = has_aff ? aff_a[c] : 1.0f;
    float d = has_aff ? aff_d[c] : 0.0f;
    Wp[c * DIM + j] = a * w;
    racc = fmaf(d, w, racc);
  }
  rvec[j] = racc;
}

// xh[N+1 x 128 bf16] = node_attr (fp32 -> bf16). Row N = zero sentinel.
// NORMAL stores: edge_gather wants these rows in L3 (R4 lesson: nt here
// pushed the next gather to HBM latency and cost more than it saved).
__global__ __launch_bounds__(256) void cast_x_kernel(
    const float* __restrict__ X, uint2* __restrict__ xh, long total4) {
  long i = blockIdx.x * 256L + threadIdx.x;
  if (i >= total4) return;
  float4 v = ((const float4*)X)[i];
  uint2 o;
  o.x = pk_bf16(v.x, v.y);
  o.y = pk_bf16(v.z, v.w);
  xh[i] = o;
}

// ag[e][c] = Binv_e * sum_{i in e} xh[i][c]. bf16 rows (256 B = 4 lines).
// 32 lanes/edge (uint2 = 4 ch/lane), 8 edge-slots per block.
// Uniform clamped-8 loop with zero sentinel row SENT: 8 independent row
// loads in flight per lane, no serial tail (R5 lesson: the tail-free loop
// is worth ~15%; the channel split is not).
__global__ __launch_bounds__(256) void edge_gather_kernel(
    const uint2* __restrict__ xh, const int* __restrict__ P,
    const int* __restrict__ adj_e, float* __restrict__ ag, int E, int SENT) {
  int slot = threadIdx.x >> 5;
  int l = threadIdx.x & 31;
  int e = blockIdx.x * 8 + slot;
  if (e >= E) return;
  int p0 = P[e], p1 = P[e + 1];
  float4 a = {0.f, 0.f, 0.f, 0.f};
  int kl = p1 - 1;
  for (int k = p0; k < p1; k += 8) {
    int n0 = adj_e[min(k, kl)];
    int n1 = (k + 1 <= kl) ? adj_e[k + 1] : SENT;
    int n2 = (k + 2 <= kl) ? adj_e[k + 2] : SENT;
    int n3 = (k + 3 <= kl) ? adj_e[k + 3] : SENT;
    int n4 = (k + 4 <= kl) ? adj_e[k + 4] : SENT;
    int n5 = (k + 5 <= kl) ? adj_e[k + 5] : SENT;
    int n6 = (k + 6 <= kl) ? adj_e[k + 6] : SENT;
    int n7 = (k + 7 <= kl) ? adj_e[k + 7] : SENT;
    uint2 q0 = xh[(size_t)n0 * 32 + l];
    uint2 q1 = xh[(size_t)n1 * 32 + l];
    uint2 q2 = xh[(size_t)n2 * 32 + l];
    uint2 q3 = xh[(size_t)n3 * 32 + l];
    uint2 q4 = xh[(size_t)n4 * 32 + l];
    uint2 q5 = xh[(size_t)n5 * 32 + l];
    uint2 q6 = xh[(size_t)n6 * 32 + l];
    uint2 q7 = xh[(size_t)n7 * 32 + l];
    a.x += ((bf_lo(q0.x) + bf_lo(q1.x)) + (bf_lo(q2.x) + bf_lo(q3.x))) +
           ((bf_lo(q4.x) + bf_lo(q5.x)) + (bf_lo(q6.x) + bf_lo(q7.x)));
    a.y += ((bf_hi(q0.x) + bf_hi(q1.x)) + (bf_hi(q2.x) + bf_hi(q3.x))) +
           ((bf_hi(q4.x) + bf_hi(q5.x)) + (bf_hi(q6.x) + bf_hi(q7.x)));
    a.z += ((bf_lo(q0.y) + bf_lo(q1.y)) + (bf_lo(q2.y) + bf_lo(q3.y))) +
           ((bf_lo(q4.y) + bf_lo(q5.y)) + (bf_lo(q6.y) + bf_lo(q7.y)));
    a.w += ((bf_hi(q0.y) + bf_hi(q1.y)) + (bf_hi(q2.y) + bf_hi(q3.y))) +
           ((bf_hi(q4.y) + bf_hi(q5.y)) + (bf_hi(q6.y) + bf_hi(q7.y)));
  }
  float binv = (p1 > p0) ? 1.0f / (float)(p1 - p0) : 0.0f;
  float4 o;
  o.x = a.x * binv; o.y = a.y * binv; o.z = a.z * binv; o.w = a.w * binv;
  ((float4*)ag)[(size_t)e * 32 + l] = o;  // linear; gemm reads it next via L3
}

// efh[E+1 x 128 bf16] = (ag @ Wp + rvec), zeroed for empty edges (deg==0).
// fp32 accumulate, bf16 pack on store. Normal stores (seed L2/L3 for
// node_gather).
__global__ __launch_bounds__(256) void gemm128_kernel(
    const float* __restrict__ X, const float* __restrict__ Wp,
    const float* __restrict__ rvec, const int* __restrict__ Pdeg,
    unsigned* __restrict__ Yh, int nrows) {
  __shared__ float sW[32 * DIM];   // sW[kk*128 + j]
  __shared__ float sX[DIM * 36];   // sX[rr*36 + kk], 36 keeps 16B align + pad
  const int t = threadIdx.x;
  const int row0 = blockIdx.x * DIM;
  const int tx = t & 15, ty = t >> 4;
  const int col0 = tx * 8, lr0 = ty * 8;
  float acc[8][8];
#pragma unroll
  for (int i = 0; i < 8; ++i)
#pragma unroll
    for (int j = 0; j < 8; ++j) acc[i][j] = 0.0f;

  for (int kc = 0; kc < 4; ++kc) {
    __syncthreads();
    {
      const float4* W4 = (const float4*)(Wp + kc * 32 * DIM);
      float4* sW4 = (float4*)sW;
#pragma unroll
      for (int i = 0; i < 4; ++i) sW4[t + i * 256] = W4[t + i * 256];
    }
#pragma unroll
    for (int i = 0; i < 4; ++i) {
      int q = t + i * 256;            // 0..1023 float4 slots
      int rr = q >> 3, kq = q & 7;
      int gr = row0 + rr; if (gr >= nrows) gr = nrows - 1;  // stores are guarded
      float4 v = *(const float4*)&X[(size_t)gr * DIM + kc * 32 + kq * 4];
      *(float4*)&sX[rr * 36 + kq * 4] = v;
    }
    __syncthreads();
    for (int kk = 0; kk < 32; ++kk) {
      float4 w0 = *(const float4*)&sW[kk * DIM + col0];
      float4 w1 = *(const float4*)&sW[kk * DIM + col0 + 4];
      float wv[8] = {w0.x, w0.y, w0.z, w0.w, w1.x, w1.y, w1.z, w1.w};
      float xv[8];
#pragma unroll
      for (int i = 0; i < 8; ++i) xv[i] = sX[(lr0 + i) * 36 + kk];
#pragma unroll
      for (int i = 0; i < 8; ++i)
#pragma unroll
        for (int j = 0; j < 8; ++j) acc[i][j] = fmaf(xv[i], wv[j], acc[i][j]);
    }
  }
  float4 r0 = *(const float4*)&rvec[col0];
  float4 r1 = *(const float4*)&rvec[col0 + 4];
#pragma unroll
  for (int i = 0; i < 8; ++i) {
    int gr = row0 + lr0 + i;
    if (gr < nrows) {
      // empty segment must produce 0 (reference: Binv=0 ⇒ e_feat=0),
      // not rvec — guard with the degree.
      float nz = (Pdeg[gr + 1] > Pdeg[gr]) ? 1.0f : 0.0f;
      float o0x = (acc[i][0] + r0.x) * nz, o0y = (acc[i][1] + r0.y) * nz;
      float o0z = (acc[i][2] + r0.z) * nz, o0w = (acc[i][3] + r0.w) * nz;
      float o1x = (acc[i][4] + r1.x) * nz, o1y = (acc[i][5] + r1.y) * nz;
      float o1z = (acc[i][6] + r1.z) * nz, o1w = (acc[i][7] + r1.w) * nz;
      uint4 st;
      st.x = pk_bf16(o0x, o0y);
      st.y = pk_bf16(o0z, o0w);
      st.z = pk_bf16(o1x, o1y);
      st.w = pk_bf16(o1z, o1w);
      *(uint4*)&Yh[(size_t)gr * 64 + (col0 >> 1)] = st;
    }
  }
}

// zh[i][c] = bf16(relu(Dinv_i * sum_{e ni i} ef[e][c] + b_c)), fused BN stats.
// Full 128-ch single pass (R5 lesson: the adjacency walk has a ~70us latency
// floor, so never walk it twice). 32 lanes/node, 8 slots/block, grid-stride.
// Uniform clamped-8 loop: 8 independent ef row loads in flight, no tail.
// Normal zh stores: next layer's edge_gather gathers them via L3.
__global__ __launch_bounds__(256) void node_gather_kernel(
    const uint2* __restrict__ ef, const int* __restrict__ P,
    const int* __restrict__ adj_n, const float* __restrict__ b,
    uint2* __restrict__ zh, float* __restrict__ sum,
    float* __restrict__ sumsq, int E, int N, int nnz, int SENT) {
  __shared__ float lsum[DIM], lsumsq[DIM];
  int t = threadIdx.x;
  if (t < DIM) { lsum[t] = 0.f; lsumsq[t] = 0.f; }
  __syncthreads();
  int slot = t >> 5;
  int l = t & 31;
  float4 bc = ((const float4*)b)[l];
  float4 s1 = {0.f, 0.f, 0.f, 0.f}, s2 = {0.f, 0.f, 0.f, 0.f};
  for (int i = blockIdx.x * 8 + slot; i < N; i += gridDim.x * 8) {
    int p0 = P[E + i] - nnz, p1 = P[E + i + 1] - nnz;
    float4 a = {0.f, 0.f, 0.f, 0.f};
    int kl = p1 - 1;
    for (int k = p0; k < p1; k += 8) {
      int e0 = adj_n[min(k, kl)];
      int e1 = (k + 1 <= kl) ? adj_n[k + 1] : SENT;
      int e2 = (k + 2 <= kl) ? adj_n[k + 2] : SENT;
      int e3 = (k + 3 <= kl) ? adj_n[k + 3] : SENT;
      int e4 = (k + 4 <= kl) ? adj_n[k + 4] : SENT;
      int e5 = (k + 5 <= kl) ? adj_n[k + 5] : SENT;
      int e6 = (k + 6 <= kl) ? adj_n[k + 6] : SENT;
      int e7 = (k + 7 <= kl) ? adj_n[k + 7] : SENT;
      uint2 q0 = ef[(size_t)e0 * 32 + l];
      uint2 q1 = ef[(size_t)e1 * 32 + l];
      uint2 q2 = ef[(size_t)e2 * 32 + l];
      uint2 q3 = ef[(size_t)e3 * 32 + l];
      uint2 q4 = ef[(size_t)e4 * 32 + l];
      uint2 q5 = ef[(size_t)e5 * 32 + l];
      uint2 q6 = ef[(size_t)e6 * 32 + l];
      uint2 q7 = ef[(size_t)e7 * 32 + l];
      a.x += ((bf_lo(q0.x) + bf_lo(q1.x)) + (bf_lo(q2.x) + bf_lo(q3.x))) +
             ((bf_lo(q4.x) + bf_lo(q5.x)) + (bf_lo(q6.x) + bf_lo(q7.x)));
      a.y += ((bf_hi(q0.x) + bf_hi(q1.x)) + (bf_hi(q2.x) + bf_hi(q3.x))) +
             ((bf_hi(q4.x) + bf_hi(q5.x)) + (bf_hi(q6.x) + bf_hi(q7.x)));
      a.z += ((bf_lo(q0.y) + bf_lo(q1.y)) + (bf_lo(q2.y) + bf_lo(q3.y))) +
             ((bf_lo(q4.y) + bf_lo(q5.y)) + (bf_lo(q6.y) + bf_lo(q7.y)));
      a.w += ((bf_hi(q0.y) + bf_hi(q1.y)) + (bf_hi(q2.y) + bf_hi(q3.y))) +
             ((bf_hi(q4.y) + bf_hi(q5.y)) + (bf_hi(q6.y) + bf_hi(q7.y)));
    }
    float dinv = (p1 > p0) ? 1.0f / (float)(p1 - p0) : 0.0f;
    float4 v;
    v.x = fmaxf(fmaf(dinv, a.x, bc.x), 0.f);
    v.y = fmaxf(fmaf(dinv, a.y, bc.y), 0.f);
    v.z = fmaxf(fmaf(dinv, a.z, bc.z), 0.f);
    v.w = fmaxf(fmaf(dinv, a.w, bc.w), 0.f);
    uint2 o;
    o.x = pk_bf16(v.x, v.y);
    o.y = pk_bf16(v.z, v.w);
    zh[(size_t)i * 32 + l] = o;
    s1.x += v.x; s1.y += v.y; s1.z += v.z; s1.w += v.w;
    s2.x = fmaf(v.x, v.x, s2.x); s2.y = fmaf(v.y, v.y, s2.y);
    s2.z = fmaf(v.z, v.z, s2.z); s2.w = fmaf(v.w, v.w, s2.w);
  }
  int c0 = l * 4;
  atomicAdd(&lsum[c0 + 0], s1.x); atomicAdd(&lsum[c0 + 1], s1.y);
  atomicAdd(&lsum[c0 + 2], s1.z); atomicAdd(&lsum[c0 + 3], s1.w);
  atomicAdd(&lsumsq[c0 + 0], s2.x); atomicAdd(&lsumsq[c0 + 1], s2.y);
  atomicAdd(&lsumsq[c0 + 2], s2.z); atomicAdd(&lsumsq[c0 + 3], s2.w);
  __syncthreads();
  if (t < DIM) {
    atomicAdd(&sum[t], lsum[t]);
    atomicAdd(&sumsq[t], lsumsq[t]);
  }
}

// aff_a = g*rsqrt(var+eps); aff_d = beta - mu*aff_a
__global__ void finalize_bn_kernel(const float* __restrict__ sum,
                                   const float* __restrict__ sumsq,
                                   const float* __restrict__ g,
                                   const float* __restrict__ beta,
                                   float* __restrict__ aff_a, float* __restrict__ aff_d,
                                   int n) {
  int c = threadIdx.x;
  float inv_n = 1.0f / (float)n;
  float mu = sum[c] * inv_n;
  float var = fmaf(sumsq[c], inv_n, -mu * mu);
  float a = g[c] * rsqrtf(var + 1e-5f);
  aff_a[c] = a;
  aff_d[c] = fmaf(-mu, a, beta[c]);
}

// out = aff_a*zh + aff_d (bf16 zh -> fp32 out, nt store: final output only)
__global__ __launch_bounds__(256) void apply_affine_kernel(
    const uint2* __restrict__ zh, const float* __restrict__ aff_a,
    const float* __restrict__ aff_d, float* __restrict__ out, long total4) {
  long i = blockIdx.x * 256L + threadIdx.x;
  if (i >= total4) return;
  int c4 = (int)(i & 31);
  float4 a = ((const float4*)aff_a)[c4];
  float4 d = ((const float4*)aff_d)[c4];
  uint2 q = zh[i];
  f32x4 o;
  o.x = fmaf(a.x, bf_lo(q.x), d.x);
  o.y = fmaf(a.y, bf_hi(q.x), d.y);
  o.z = fmaf(a.z, bf_lo(q.y), d.z);
  o.w = fmaf(a.w, bf_hi(q.y), d.w);
  __builtin_nontemporal_store(o, &((f32x4*)out)[i]);
}

extern "C" void kernel_launch(void* const* d_in, const int* in_sizes, int n_in,
                              void* d_out, int out_size, void* d_ws, size_t ws_size,
                              hipStream_t stream) {
  const int NNZv = in_sizes[0] / 2;
  const int Nv   = in_sizes[1] / DIM;
  const int Ev   = in_sizes[2] / DIM;
  const int* eidx_raw = (const int*)d_in[0];
  const float* node_attr = (const float*)d_in[1];

  // ---- workspace layout (~47 MB total) ----
  float* bufE  = (float*)d_ws;                 // E*128 f32 (ag)
  float* Wp    = bufE + (size_t)Ev * DIM;      // 128*128
  float* rvec  = Wp + DIM * DIM;               // 128
  float* sums  = rvec + 128;                   // 128
  float* sumsq = sums + 128;                   // 128
  float* aff_a = sumsq + 128;                  // 128
  float* aff_d = aff_a + 128;                  // 128
  // src/edg/cnt dead after fill_adj -> reused as efh: (E+1)*64 uints
  // (row E = zero sentinel) = 5.12 MB <= src+edg+cnt region (5.28 MB).
  int* src   = (int*)(aff_d + 128);            // NNZ
  int* edg   = src + NNZv;                     // NNZ
  int* cnt   = edg + NNZv;                     // E+N (padded to x4)
  int* P     = cnt + (((size_t)Ev + Nv + 3) & ~(size_t)3);  // E+N+1 (padded)
  int* BS    = P + (((size_t)Ev + Nv + 1 + 3) & ~(size_t)3); // <=256 block sums
  int* adj_e = BS + 256;                       // NNZ
  int* adj_n = adj_e + NNZv;                   // NNZ
  unsigned* efh = (unsigned*)src;              // (E+1)*64 uints (bf16 ef rows)
  uint2* xh = (uint2*)(adj_n + NNZv);          // (N+1)*32 uint2 (bf16 x / z)

  const int M = Ev + Nv;
  const int nbA = cdiv(M, 1024);

  convert_idx_kernel<<<cdiv(2L * NNZv, 256), 256, 0, stream>>>(eidx_raw, src, 2L * NNZv);
  hipMemsetAsync(cnt, 0, (size_t)M * 4, stream);
  count_kernel<<<cdiv(NNZv, 256), 256, 0, stream>>>(src, edg, cnt, Ev, NNZv);
  scanA_kernel<<<nbA, 256, 0, stream>>>(cnt, P, BS, M);
  scanB_kernel<<<1, 64, 0, stream>>>(BS, P, nbA, M);
  scanC_kernel<<<cdiv(M, 256), 256, 0, stream>>>(P, BS, M);
  hipMemsetAsync(cnt, 0, (size_t)M * 4, stream);
  fill_adj_kernel<<<cdiv(NNZv, 256), 256, 0, stream>>>(src, edg, P, cnt, adj_e, adj_n, Ev, NNZv);
  cast_x_kernel<<<cdiv((long)Nv * 32, 256), 256, 0, stream>>>(node_attr, xh, (long)Nv * 32);
  // zero sentinel rows (edge row E, node row N) used by the clamped gathers
  hipMemsetAsync(efh + (size_t)Ev * 64, 0, 256, stream);
  hipMemsetAsync(xh + (size_t)Nv * 32, 0, 256, stream);

  for (int l = 0; l < 3; ++l) {
    const float* W    = (const float*)d_in[3 + l * 4];
    const float* b    = (const float*)d_in[4 + l * 4];
    const float* g    = (const float*)d_in[5 + l * 4];
    const float* beta = (const float*)d_in[6 + l * 4];

    prep_w_kernel<<<1, 128, 0, stream>>>(W, aff_a, aff_d, Wp, rvec, l > 0 ? 1 : 0);
    edge_gather_kernel<<<cdiv(Ev, 8), 256, 0, stream>>>(xh, P, adj_e, bufE, Ev, Nv);
    gemm128_kernel<<<cdiv(Ev, DIM), 256, 0, stream>>>(bufE, Wp, rvec, P, efh, Ev);
    hipMemsetAsync(sums, 0, 256 * 4, stream);
    node_gather_kernel<<<2048, 256, 0, stream>>>(
        (const uint2*)efh, P, adj_n, b, xh, sums, sumsq, Ev, Nv, NNZv, Ev);
    finalize_bn_kernel<<<1, 128, 0, stream>>>(sums, sumsq, g, beta, aff_a, aff_d, Nv);
  }
  apply_affine_kernel<<<cdiv((long)Nv * 32, 256), 256, 0, stream>>>(
      xh, aff_a, aff_d, (float*)d_out, (long)Nv * 32);
}